// Round 1
// baseline (697.797 us; speedup 1.0000x reference)
//
#include <hip/hip_runtime.h>
#include <math.h>

#define V 50000
#define E 300
#define H 2048
#define L 512
#define EH 2348  // E+H

// ---------------- kernel 1: attention scores = cat(emb_row, h0) @ attn_W.T + attn_b
__global__ void k_attn_scores(const int* __restrict__ token, const float* __restrict__ h0,
                              const float* __restrict__ emb, const float* __restrict__ attn_W,
                              const float* __restrict__ attn_b, float* __restrict__ scores) {
    int row = blockIdx.x;
    int tid = threadIdx.x;
    const float* erow = emb + (size_t)token[0] * E;
    const float* wrow = attn_W + (size_t)row * EH;
    float acc = 0.f;
    for (int j = tid; j < EH; j += 256) {
        float c = (j < E) ? erow[j] : h0[j - E];
        acc += c * wrow[j];
    }
    __shared__ float red[256];
    red[tid] = acc; __syncthreads();
    for (int s = 128; s > 0; s >>= 1) {
        if (tid < s) red[tid] += red[tid + s];
        __syncthreads();
    }
    if (tid == 0) scores[row] = red[0] + attn_b[row];
}

// ---------------- kernel 2: softmax over 512 scores (single block, 512 threads)
__global__ void k_softmax(const float* __restrict__ scores, float* __restrict__ attnw,
                          float* __restrict__ out_attnw) {
    int tid = threadIdx.x;
    float v = scores[tid];
    __shared__ float red[512];
    red[tid] = v; __syncthreads();
    for (int s = 256; s > 0; s >>= 1) { if (tid < s) red[tid] = fmaxf(red[tid], red[tid + s]); __syncthreads(); }
    float m = red[0]; __syncthreads();
    float e = expf(v - m);
    red[tid] = e; __syncthreads();
    for (int s = 256; s > 0; s >>= 1) { if (tid < s) red[tid] += red[tid + s]; __syncthreads(); }
    float w = e / red[0];
    attnw[tid] = w;
    out_attnw[tid] = w;
}

// ---------------- kernel 3: attn_applied[h] = sum_l w[l] * enc[l][h]   (coalesced over h)
__global__ void k_attn_apply(const float* __restrict__ attnw, const float* __restrict__ enc,
                             float* __restrict__ out) {
    __shared__ float w[L];
    int tid = threadIdx.x;
    for (int i = tid; i < L; i += 256) w[i] = attnw[i];
    __syncthreads();
    int h = blockIdx.x * 256 + tid;
    float acc = 0.f;
    for (int l = 0; l < L; ++l) acc += w[l] * enc[(size_t)l * H + h];
    out[h] = acc;
}

// ---------------- kernel 4: x = relu(cat(emb_row, attn_applied) @ comb_W.T + comb_b)
__global__ void k_combine(const int* __restrict__ token, const float* __restrict__ emb,
                          const float* __restrict__ attn_applied, const float* __restrict__ comb_W,
                          const float* __restrict__ comb_b, float* __restrict__ x) {
    int row = blockIdx.x;
    int tid = threadIdx.x;
    const float* erow = emb + (size_t)token[0] * E;
    const float* wrow = comb_W + (size_t)row * EH;
    float acc = 0.f;
    for (int j = tid; j < EH; j += 256) {
        float c = (j < E) ? erow[j] : attn_applied[j - E];
        acc += c * wrow[j];
    }
    __shared__ float red[256];
    red[tid] = acc; __syncthreads();
    for (int s = 128; s > 0; s >>= 1) {
        if (tid < s) red[tid] += red[tid + s];
        __syncthreads();
    }
    if (tid == 0) x[row] = fmaxf(red[0] + comb_b[row], 0.f);
}

// ---------------- kernel 5: fused GRU input+hidden GEMV, wave-per-row, float4
__global__ void k_gru_gemv(const float* __restrict__ x, const float* __restrict__ h0,
                           const float* __restrict__ W_ih, const float* __restrict__ W_hh,
                           const float* __restrict__ b_ih, const float* __restrict__ b_hh,
                           float* __restrict__ gi, float* __restrict__ gh) {
    int lane = threadIdx.x & 63;
    int wave = (blockIdx.x * blockDim.x + threadIdx.x) >> 6;
    int nw = (gridDim.x * blockDim.x) >> 6;
    const float4* x4 = (const float4*)x;
    const float4* h4 = (const float4*)h0;
    float4 xr[8], hr[8];
    #pragma unroll
    for (int i = 0; i < 8; i++) { xr[i] = x4[i * 64 + lane]; hr[i] = h4[i * 64 + lane]; }
    for (int r = wave; r < 2 * 3 * H; r += nw) {
        bool is_i = r < 3 * H;               // wave-uniform branch
        int row = is_i ? r : r - 3 * H;
        const float4* wrow = (const float4*)((is_i ? W_ih : W_hh) + (size_t)row * H);
        float acc = 0.f;
        #pragma unroll
        for (int i = 0; i < 8; i++) {
            float4 w = wrow[i * 64 + lane];
            float4 v = is_i ? xr[i] : hr[i];
            acc += v.x * w.x + v.y * w.y + v.z * w.z + v.w * w.w;
        }
        #pragma unroll
        for (int off = 32; off > 0; off >>= 1) acc += __shfl_xor(acc, off, 64);
        if (lane == 0) {
            if (is_i) gi[row] = acc + b_ih[row];
            else      gh[row] = acc + b_hh[row];
        }
    }
}

// ---------------- kernel 6: GRU elementwise -> h_new (written directly to d_out slot)
__global__ void k_gru_elem(const float* __restrict__ gi, const float* __restrict__ gh,
                           const float* __restrict__ h0, float* __restrict__ hnew) {
    int h = blockIdx.x * 256 + threadIdx.x;
    float r = 1.f / (1.f + expf(-(gi[h] + gh[h])));
    float z = 1.f / (1.f + expf(-(gi[H + h] + gh[H + h])));
    float n = tanhf(gi[2 * H + h] + r * gh[2 * H + h]);
    hnew[h] = (1.f - z) * n + z * h0[h];
}

// ---------------- kernel 7: logits = h_new @ out_W.T + out_b  (the 410 MB GEMV)
__global__ void k_out_gemv(const float* __restrict__ hnew, const float* __restrict__ out_W,
                           const float* __restrict__ out_b, float* __restrict__ logits) {
    int lane = threadIdx.x & 63;
    int wave = (blockIdx.x * blockDim.x + threadIdx.x) >> 6;
    int nw = (gridDim.x * blockDim.x) >> 6;
    const float4* h4 = (const float4*)hnew;
    float4 hreg[8];
    #pragma unroll
    for (int i = 0; i < 8; i++) hreg[i] = h4[i * 64 + lane];
    for (int r = wave; r < V; r += nw) {
        const float4* wrow = (const float4*)(out_W + (size_t)r * H);
        float acc = 0.f;
        #pragma unroll
        for (int i = 0; i < 8; i++) {
            float4 w = wrow[i * 64 + lane];
            acc += hreg[i].x * w.x + hreg[i].y * w.y + hreg[i].z * w.z + hreg[i].w * w.w;
        }
        #pragma unroll
        for (int off = 32; off > 0; off >>= 1) acc += __shfl_xor(acc, off, 64);
        if (lane == 0) logits[r] = acc + out_b[r];
    }
}

// ---------------- kernel 8: single-block max + logsumexp over 50k logits
__global__ void k_lse(const float* __restrict__ logits, float* __restrict__ C) {
    int tid = threadIdx.x;
    __shared__ float red[1024];
    float m = -1e30f;
    for (int i = tid; i < V; i += 1024) m = fmaxf(m, logits[i]);
    red[tid] = m; __syncthreads();
    for (int s = 512; s > 0; s >>= 1) { if (tid < s) red[tid] = fmaxf(red[tid], red[tid + s]); __syncthreads(); }
    m = red[0]; __syncthreads();
    float sum = 0.f;
    for (int i = tid; i < V; i += 1024) sum += expf(logits[i] - m);
    red[tid] = sum; __syncthreads();
    for (int s = 512; s > 0; s >>= 1) { if (tid < s) red[tid] += red[tid + s]; __syncthreads(); }
    if (tid == 0) C[0] = m + logf(red[0]);
}

// ---------------- kernel 9: final log_softmax write
__global__ void k_logsoftmax(const float* __restrict__ logits, const float* __restrict__ C,
                             float* __restrict__ out) {
    int i = blockIdx.x * 256 + threadIdx.x;
    if (i < V) out[i] = logits[i] - C[0];
}

extern "C" void kernel_launch(void* const* d_in, const int* in_sizes, int n_in,
                              void* d_out, int out_size, void* d_ws, size_t ws_size,
                              hipStream_t stream) {
    const int*   token  = (const int*)d_in[0];
    const float* hidden = (const float*)d_in[1];   // [1,1,H]
    const float* enc    = (const float*)d_in[2];   // [L,H]
    const float* emb    = (const float*)d_in[3];   // [V,E]
    const float* attn_W = (const float*)d_in[4];   // [L,EH]
    const float* attn_b = (const float*)d_in[5];   // [L]
    const float* comb_W = (const float*)d_in[6];   // [H,EH]
    const float* comb_b = (const float*)d_in[7];   // [H]
    const float* W_ih   = (const float*)d_in[8];   // [3H,H]
    const float* W_hh   = (const float*)d_in[9];   // [3H,H]
    const float* b_ih   = (const float*)d_in[10];  // [3H]
    const float* b_hh   = (const float*)d_in[11];  // [3H]
    const float* out_W  = (const float*)d_in[12];  // [V,H]
    const float* out_b  = (const float*)d_in[13];  // [V]

    float* out = (float*)d_out;
    float* ws  = (float*)d_ws;

    // ws layout (floats)
    float* scores = ws;            // 512
    float* attnw  = ws + 512;      // 512
    float* attnap = ws + 1024;     // 2048
    float* xvec   = ws + 4096;     // 2048
    float* gi     = ws + 8192;     // 6144
    float* gh     = ws + 14336;    // 6144
    float* logits = ws + 20480;    // 50000
    float* Cc     = ws + 70528;    // 1

    // d_out layout: output[50000] | h_new[2048] | attn_weights[512]
    float* out_logits = out;
    float* out_h      = out + V;
    float* out_attnw  = out + V + H;

    k_attn_scores<<<512, 256, 0, stream>>>(token, hidden, emb, attn_W, attn_b, scores);
    k_softmax<<<1, 512, 0, stream>>>(scores, attnw, out_attnw);
    k_attn_apply<<<8, 256, 0, stream>>>(attnw, enc, attnap);
    k_combine<<<2048, 256, 0, stream>>>(token, emb, attnap, comb_W, comb_b, xvec);
    k_gru_gemv<<<512, 256, 0, stream>>>(xvec, hidden, W_ih, W_hh, b_ih, b_hh, gi, gh);
    k_gru_elem<<<8, 256, 0, stream>>>(gi, gh, hidden, out_h);
    k_out_gemv<<<1024, 256, 0, stream>>>(out_h, out_W, out_b, logits);
    k_lse<<<1, 1024, 0, stream>>>(logits, Cc);
    k_logsoftmax<<<196, 256, 0, stream>>>(logits, Cc, out_logits);
}